// Round 12
// baseline (804.863 us; speedup 1.0000x reference)
//
#include <hip/hip_runtime.h>
#include <math.h>

#define NPTS 262144
#define KC 512
#define DD 64
#define MARGIN 0.05f
#define SHIFT 32.0f
#define SENTINEL -1.0f

typedef _Float16 f16x8 __attribute__((ext_vector_type(8)));
typedef float f32x4 __attribute__((ext_vector_type(4)));

// ws layout (bytes) -- same ~70 KB region R4/R11 used successfully
#define WS_CS16  16     // 512 f32: c_sq + SHIFT
#define WS_CSQ   2064   // 512 f32: exact c_sq (pairwise-8, for rescore)
#define WS_CF16  4112   // 512*64 f16 centroids

__device__ __forceinline__ float csq_pairwise8(const float* row) {
    float r[8];
#pragma unroll
    for (int t = 0; t < 8; ++t) r[t] = __fmul_rn(row[t], row[t]);
#pragma unroll
    for (int b = 1; b < 8; ++b)
#pragma unroll
        for (int t = 0; t < 8; ++t)
            r[t] = __fadd_rn(r[t], __fmul_rn(row[8 * b + t], row[8 * b + t]));
    return __fadd_rn(__fadd_rn(__fadd_rn(r[0], r[1]), __fadd_rn(r[2], r[3])),
                     __fadd_rn(__fadd_rn(r[4], r[5]), __fadd_rn(r[6], r[7])));
}

// Prep: centroid passthrough, f16 conversion (approx staging = pure copy),
// c_sq exact (np pairwise-8) and c_sq+SHIFT.
__global__ __launch_bounds__(256) void prep_kernel(const float* __restrict__ c,
                                                   float* __restrict__ out_c,
                                                   _Float16* __restrict__ cf16,
                                                   float* __restrict__ cs16,
                                                   float* __restrict__ csq) {
    int j = blockIdx.x * 256 + threadIdx.x;
    if (j < KC * DD) {
        float v = c[j];
        out_c[j] = v;
        cf16[j] = (_Float16)v;  // RNE
    }
    if (j < KC) {
        float s = csq_pairwise8(c + j * DD);
        csq[j] = s;
        cs16[j] = s + SHIFT;
    }
}

// EXACT R4 approx structure (the only MFMA build measured spill-free:
// VGPR=32, WRITE 1.7 MB) MINUS the things that broke R4/R6-R11:
//  - NO in-kernel rescore tail (R11 proved it triggers 700 MB kernel-wide
//    spill), NO atomics (R4's 280us was a single-address atomic storm),
//    NO flag list. Ambiguous points get a SENTINEL in out_assign; a separate
//    cleanup kernel repairs them. Branchless single write per element.
//  - SHIFT=32 (R8-proven): d' = c_sq+32-2*cross in (12,52) > 0 -> uint order
//    == float order; packed key (distbits&~0x1FF)|k, stripped ties -> smaller
//    k; any possible misorder has stripped-gap <= MARGIN -> flagged.
__global__ __launch_bounds__(256, 2) void approx_kernel(const float* __restrict__ x,
                                                        const _Float16* __restrict__ cf16,
                                                        const float* __restrict__ cs16g,
                                                        float* __restrict__ out_assign) {
    extern __shared__ char smem[];          // [0,64K): swizzled c_f16
    float* scs = (float*)(smem + 65536);    // 512 f32: c_sq + SHIFT

    int tid = threadIdx.x;
    // Stage centroids f16, XOR-swizzled (R4-proven): row stride 128B would be
    // a 16-way bank conflict on ds_read_b128; slot^(row&7) spreads rows.
    const uint4* src = (const uint4*)cf16;
#pragma unroll
    for (int i = 0; i < 16; ++i) {
        int chunk = tid + i * 256;          // 4096 chunks of 16B
        int row = chunk >> 3, slot = chunk & 7;
        uint4 v = src[chunk];
        *(uint4*)(smem + row * 128 + ((slot ^ (row & 7)) << 4)) = v;
    }
    scs[tid] = cs16g[tid];
    scs[tid + 256] = cs16g[tid + 256];
    __syncthreads();

    int wid = tid >> 6, lane = tid & 63;
    int pbase = blockIdx.x * 128 + wid * 32;
    int lrow = lane & 15, lgrp = lane >> 4;

    // A-frags (layout proven absmax=0 R4-R11): lane holds A[row=lane&15]
    // [k=(lane>>4)*8+i]; two point-sets s, two K-chunks kk.
    f16x8 a[2][2];
#pragma unroll
    for (int s = 0; s < 2; ++s)
#pragma unroll
        for (int kk = 0; kk < 2; ++kk) {
            const float4* p = (const float4*)(x + (size_t)(pbase + s * 16 + lrow) * DD
                                              + kk * 32 + lgrp * 8);
            float4 u0 = p[0], u1 = p[1];
            f16x8 t;
            t[0] = (_Float16)u0.x; t[1] = (_Float16)u0.y;
            t[2] = (_Float16)u0.z; t[3] = (_Float16)u0.w;
            t[4] = (_Float16)u1.x; t[5] = (_Float16)u1.y;
            t[6] = (_Float16)u1.z; t[7] = (_Float16)u1.w;
            a[s][kk] = t;
        }

    unsigned b1[2][4], b2[2][4];
#pragma unroll
    for (int s = 0; s < 2; ++s)
#pragma unroll
        for (int r = 0; r < 4; ++r) { b1[s][r] = 0xFFFFFFFFu; b2[s][r] = 0xFFFFFFFFu; }

    int base0 = lrow * 128 + ((lgrp ^ (lane & 7)) << 4);       // kk=0
    int base1 = base0 ^ 64;                                    // kk=1
    int centv = lrow;

    for (int ct = 0; ct < 32; ++ct) {
        f16x8 bk0 = *(const f16x8*)(smem + base0);
        f16x8 bk1 = *(const f16x8*)(smem + base1);
        float cs = scs[centv];
        f32x4 acc0 = {0.f, 0.f, 0.f, 0.f}, acc1 = {0.f, 0.f, 0.f, 0.f};
        acc0 = __builtin_amdgcn_mfma_f32_16x16x32_f16(a[0][0], bk0, acc0, 0, 0, 0);
        acc0 = __builtin_amdgcn_mfma_f32_16x16x32_f16(a[0][1], bk1, acc0, 0, 0, 0);
        acc1 = __builtin_amdgcn_mfma_f32_16x16x32_f16(a[1][0], bk0, acc1, 0, 0, 0);
        acc1 = __builtin_amdgcn_mfma_f32_16x16x32_f16(a[1][1], bk1, acc1, 0, 0, 0);
#pragma unroll
        for (int r = 0; r < 4; ++r) {
            float d0 = __builtin_fmaf(-2.0f, acc0[r], cs);
            float d1 = __builtin_fmaf(-2.0f, acc1[r], cs);
            unsigned k0 = (__float_as_uint(d0) & 0xFFFFFE00u) | (unsigned)centv;
            unsigned k1 = (__float_as_uint(d1) & 0xFFFFFE00u) | (unsigned)centv;
            unsigned m0 = max(b1[0][r], k0);
            b1[0][r] = min(b1[0][r], k0);
            b2[0][r] = min(b2[0][r], m0);
            unsigned m1 = max(b1[1][r], k1);
            b1[1][r] = min(b1[1][r], k1);
            b2[1][r] = min(b2[1][r], m1);
        }
        base0 += 2048; base1 += 2048; centv += 16;
    }

    // Best-2 merge across the 16 lanes of each row-group (xor butterfly).
#pragma unroll
    for (int d = 1; d < 16; d <<= 1) {
#pragma unroll
        for (int s = 0; s < 2; ++s)
#pragma unroll
            for (int r = 0; r < 4; ++r) {
                unsigned o1 = (unsigned)__shfl_xor((int)b1[s][r], d);
                unsigned o2 = (unsigned)__shfl_xor((int)b2[s][r], d);
                unsigned mx = max(b1[s][r], o1);
                b1[s][r] = min(b1[s][r], o1);
                b2[s][r] = min(min(b2[s][r], o2), mx);
            }
    }

    // Write phase: branchless, one write per element, no atomics, no lists.
    // Ambiguous -> SENTINEL (repaired by cleanup_kernel).
    if (lrow == 0) {
#pragma unroll
        for (int s = 0; s < 2; ++s)
#pragma unroll
            for (int r = 0; r < 4; ++r) {
                int p = pbase + s * 16 + lgrp * 4 + r;     // C/D row=(lane>>4)*4+reg
                unsigned w = b1[s][r];
                float d1 = __uint_as_float(w & 0xFFFFFE00u);
                float d2 = __uint_as_float(b2[s][r] & 0xFFFFFE00u);
                float kf = (float)(w & 0x1FFu);
                out_assign[p] = (d2 - d1 <= MARGIN) ? SENTINEL : kf;
            }
    }
}

// Cleanup: coalesced scan for sentinels; each flagged point rescored by a
// full wave (lanes own 8 centroids each) with the bit-exact np-replica
// distance (proven absmax=0 R1-R11). Register pressure isolated here, away
// from the MFMA kernel (R11: co-located tail -> 700 MB kernel-wide spill).
__global__ __launch_bounds__(256) void cleanup_kernel(const float* __restrict__ x,
                                                      const float* __restrict__ c,
                                                      const float* __restrict__ csq,
                                                      float* __restrict__ out_assign) {
    int p = blockIdx.x * 256 + threadIdx.x;
    int lane = threadIdx.x & 63;
    float v = out_assign[p];
    unsigned long long mask = __ballot(v < 0.0f);
    int wbase = p & ~63;   // wave's first point

    while (mask) {
        int b = __ffsll((long long)mask) - 1;
        mask &= mask - 1;
        int i = wbase + b;
        const float* xr = x + (size_t)i * DD;   // wave-uniform -> s_loads

        float r8[8];
#pragma unroll
        for (int e = 0; e < 8; ++e) r8[e] = __fmul_rn(xr[e], xr[e]);
#pragma unroll
        for (int blk = 1; blk < 8; ++blk)
#pragma unroll
            for (int e = 0; e < 8; ++e)
                r8[e] = __fadd_rn(r8[e], __fmul_rn(xr[8 * blk + e], xr[8 * blk + e]));
        float x_sq = __fadd_rn(__fadd_rn(__fadd_rn(r8[0], r8[1]), __fadd_rn(r8[2], r8[3])),
                               __fadd_rn(__fadd_rn(r8[4], r8[5]), __fadd_rn(r8[6], r8[7])));

        unsigned long long best = ~0ull;
#pragma unroll 1
        for (int j = 0; j < 8; ++j) {           // unroll 1: cap pressure
            int k = j * 64 + lane;
            const float* crow = c + (size_t)k * DD;
            float a0 = 0.f, a1 = 0.f, a2 = 0.f, a3 = 0.f;
#pragma unroll
            for (int d = 0; d < DD; d += 4) {
                a0 = __fmaf_rn(xr[d + 0], crow[d + 0], a0);
                a1 = __fmaf_rn(xr[d + 1], crow[d + 1], a1);
                a2 = __fmaf_rn(xr[d + 2], crow[d + 2], a2);
                a3 = __fmaf_rn(xr[d + 3], crow[d + 3], a3);
            }
            float acc = __fadd_rn(__fadd_rn(a0, a1), __fadd_rn(a2, a3));
            float tt = __fadd_rn(x_sq, csq[k]);
            float dist = __fmaf_rn(-2.0f, acc, tt);
            unsigned long long key =
                ((unsigned long long)__float_as_uint(dist) << 32) | (unsigned)k;
            best = best < key ? best : key;
        }
#pragma unroll
        for (int dd = 1; dd < 64; dd <<= 1) {
            unsigned hi = (unsigned)__shfl_xor((int)(best >> 32), dd);
            unsigned lo = (unsigned)__shfl_xor((int)(best & 0xFFFFFFFFull), dd);
            unsigned long long o = ((unsigned long long)hi << 32) | lo;
            best = best < o ? best : o;
        }
        if (lane == 0) out_assign[i] = (float)(unsigned)(best & 0xFFFFFFFFull);
    }
}

extern "C" void kernel_launch(void* const* d_in, const int* in_sizes, int n_in,
                              void* d_out, int out_size, void* d_ws, size_t ws_size,
                              hipStream_t stream) {
    const float* x = (const float*)d_in[0];
    const float* c = (const float*)d_in[1];
    float* out = (float*)d_out;
    float* out_assign = out + KC * DD;

    char* ws = (char*)d_ws;
    float* cs16 = (float*)(ws + WS_CS16);
    float* csq = (float*)(ws + WS_CSQ);
    _Float16* cf16 = (_Float16*)(ws + WS_CF16);

    prep_kernel<<<(KC * DD + 255) / 256, 256, 0, stream>>>(c, out, cf16, cs16, csq);
    approx_kernel<<<NPTS / 128, 256, 67584, stream>>>(x, cf16, cs16, out_assign);
    cleanup_kernel<<<NPTS / 256, 256, 0, stream>>>(x, c, csq, out_assign);
}

// Round 13
// 348.386 us; speedup vs baseline: 2.3103x; 2.3103x over previous
//
#include <hip/hip_runtime.h>
#include <math.h>

#define NPTS 262144
#define KC 512
#define DD 64
#define MARGIN 0.02f
#define SHIFT 32.0f
#define SENTINEL -1.0f

typedef _Float16 f16x8 __attribute__((ext_vector_type(8)));
typedef float f32x4 __attribute__((ext_vector_type(4)));

// ws layout (bytes)
#define WS_GCNT  0      // int global list counter (memset each launch)
#define WS_CS16  16     // 512 f32: c_sq + SHIFT
#define WS_CSQ   2064   // 512 f32: exact c_sq (pairwise-8)
#define WS_CF16  4112   // 512*64 f16 centroids (65536 B)
#define WS_LIST  69648  // compact flagged-point list (ws-size-guarded)

__device__ __forceinline__ float csq_pairwise8(const float* row) {
    float r[8];
#pragma unroll
    for (int t = 0; t < 8; ++t) r[t] = __fmul_rn(row[t], row[t]);
#pragma unroll
    for (int b = 1; b < 8; ++b)
#pragma unroll
        for (int t = 0; t < 8; ++t)
            r[t] = __fadd_rn(r[t], __fmul_rn(row[8 * b + t], row[8 * b + t]));
    return __fadd_rn(__fadd_rn(__fadd_rn(r[0], r[1]), __fadd_rn(r[2], r[3])),
                     __fadd_rn(__fadd_rn(r[4], r[5]), __fadd_rn(r[6], r[7])));
}

__global__ __launch_bounds__(256) void prep_kernel(const float* __restrict__ c,
                                                   float* __restrict__ out_c,
                                                   _Float16* __restrict__ cf16,
                                                   float* __restrict__ cs16,
                                                   float* __restrict__ csq) {
    int j = blockIdx.x * 256 + threadIdx.x;
    if (j < KC * DD) {
        float v = c[j];
        out_c[j] = v;
        cf16[j] = (_Float16)v;  // RNE
    }
    if (j < KC) {
        float s = csq_pairwise8(c + j * DD);
        csq[j] = s;
        cs16[j] = s + SHIFT;
    }
}

// R12's clean approx core (no rescore tail -> no spill) + compaction tail:
// flagged points collect in a <=128-entry LDS list, ONE global atomicAdd per
// block reserves list space (2048 total -- not R4's per-point storm), guarded
// by list_cap (the R5 ws-overflow lesson); overflow -> SENTINEL for fallback.
// Approx k is ALWAYS written; the rescore kernel overwrites flagged points
// with the exact answer -> final state deterministic across replays.
__global__ __launch_bounds__(256, 2) void approx_kernel(const float* __restrict__ x,
                                                        const _Float16* __restrict__ cf16,
                                                        const float* __restrict__ cs16g,
                                                        float* __restrict__ out_assign,
                                                        int* __restrict__ gcnt,
                                                        int* __restrict__ glist,
                                                        int list_cap) {
    extern __shared__ char smem[];          // [0,64K): swizzled c_f16
    float* scs = (float*)(smem + 65536);    // 512 f32: c_sq + SHIFT
    __shared__ int llist[128];
    __shared__ int lcnt, lbase;

    int tid = threadIdx.x;
    if (tid == 0) lcnt = 0;
    // Stage centroids f16, XOR-swizzled (R4/R12-proven).
    const uint4* src = (const uint4*)cf16;
#pragma unroll
    for (int i = 0; i < 16; ++i) {
        int chunk = tid + i * 256;          // 4096 chunks of 16B
        int row = chunk >> 3, slot = chunk & 7;
        uint4 v = src[chunk];
        *(uint4*)(smem + row * 128 + ((slot ^ (row & 7)) << 4)) = v;
    }
    scs[tid] = cs16g[tid];
    scs[tid + 256] = cs16g[tid + 256];
    __syncthreads();

    int wid = tid >> 6, lane = tid & 63;
    int pbase = blockIdx.x * 128 + wid * 32;
    int lrow = lane & 15, lgrp = lane >> 4;

    // A-frags (layout proven absmax=0 R4-R12).
    f16x8 a[2][2];
#pragma unroll
    for (int s = 0; s < 2; ++s)
#pragma unroll
        for (int kk = 0; kk < 2; ++kk) {
            const float4* p = (const float4*)(x + (size_t)(pbase + s * 16 + lrow) * DD
                                              + kk * 32 + lgrp * 8);
            float4 u0 = p[0], u1 = p[1];
            f16x8 t;
            t[0] = (_Float16)u0.x; t[1] = (_Float16)u0.y;
            t[2] = (_Float16)u0.z; t[3] = (_Float16)u0.w;
            t[4] = (_Float16)u1.x; t[5] = (_Float16)u1.y;
            t[6] = (_Float16)u1.z; t[7] = (_Float16)u1.w;
            a[s][kk] = t;
        }

    unsigned b1[2][4], b2[2][4];
#pragma unroll
    for (int s = 0; s < 2; ++s)
#pragma unroll
        for (int r = 0; r < 4; ++r) { b1[s][r] = 0xFFFFFFFFu; b2[s][r] = 0xFFFFFFFFu; }

    int base0 = lrow * 128 + ((lgrp ^ (lane & 7)) << 4);       // kk=0
    int base1 = base0 ^ 64;                                    // kk=1
    int centv = lrow;

    for (int ct = 0; ct < 32; ++ct) {
        f16x8 bk0 = *(const f16x8*)(smem + base0);
        f16x8 bk1 = *(const f16x8*)(smem + base1);
        float cs = scs[centv];
        f32x4 acc0 = {0.f, 0.f, 0.f, 0.f}, acc1 = {0.f, 0.f, 0.f, 0.f};
        acc0 = __builtin_amdgcn_mfma_f32_16x16x32_f16(a[0][0], bk0, acc0, 0, 0, 0);
        acc0 = __builtin_amdgcn_mfma_f32_16x16x32_f16(a[0][1], bk1, acc0, 0, 0, 0);
        acc1 = __builtin_amdgcn_mfma_f32_16x16x32_f16(a[1][0], bk0, acc1, 0, 0, 0);
        acc1 = __builtin_amdgcn_mfma_f32_16x16x32_f16(a[1][1], bk1, acc1, 0, 0, 0);
#pragma unroll
        for (int r = 0; r < 4; ++r) {
            float d0 = __builtin_fmaf(-2.0f, acc0[r], cs);
            float d1 = __builtin_fmaf(-2.0f, acc1[r], cs);
            unsigned k0 = (__float_as_uint(d0) & 0xFFFFFE00u) | (unsigned)centv;
            unsigned k1 = (__float_as_uint(d1) & 0xFFFFFE00u) | (unsigned)centv;
            unsigned m0 = max(b1[0][r], k0);
            b1[0][r] = min(b1[0][r], k0);
            b2[0][r] = min(b2[0][r], m0);
            unsigned m1 = max(b1[1][r], k1);
            b1[1][r] = min(b1[1][r], k1);
            b2[1][r] = min(b2[1][r], m1);
        }
        base0 += 2048; base1 += 2048; centv += 16;
    }

#pragma unroll
    for (int d = 1; d < 16; d <<= 1) {
#pragma unroll
        for (int s = 0; s < 2; ++s)
#pragma unroll
            for (int r = 0; r < 4; ++r) {
                unsigned o1 = (unsigned)__shfl_xor((int)b1[s][r], d);
                unsigned o2 = (unsigned)__shfl_xor((int)b2[s][r], d);
                unsigned mx = max(b1[s][r], o1);
                b1[s][r] = min(b1[s][r], o1);
                b2[s][r] = min(min(b2[s][r], o2), mx);
            }
    }

    // Write approx k for EVERY point; flagged also enqueue to LDS list
    // (max 4 waves x 4 lanes x 8 = 128 entries, cannot overflow).
    if (lrow == 0) {
#pragma unroll
        for (int s = 0; s < 2; ++s)
#pragma unroll
            for (int r = 0; r < 4; ++r) {
                int p = pbase + s * 16 + lgrp * 4 + r;     // C/D row=(lane>>4)*4+reg
                unsigned w = b1[s][r];
                float d1 = __uint_as_float(w & 0xFFFFFE00u);
                float d2 = __uint_as_float(b2[s][r] & 0xFFFFFE00u);
                out_assign[p] = (float)(w & 0x1FFu);
                if (d2 - d1 <= MARGIN) {
                    int t = atomicAdd(&lcnt, 1);
                    llist[t] = p;
                }
            }
    }
    __syncthreads();
    int n = lcnt;
    if (tid == 0) lbase = n ? atomicAdd(gcnt, n) : 0;
    __syncthreads();
    for (int t = tid; t < n; t += 256) {
        int idx = lbase + t;
        if (idx < list_cap) glist[idx] = llist[t];
        else out_assign[llist[t]] = SENTINEL;   // ws too small: fallback fixes
    }
}

// Rescore: thread-per-flagged-point over the COMPACT list, R1 structure
// (k-loop wave-uniform -> centroid rows come in as s_loads shared by the
// wave; proven 0.9us/point and absmax=0 in R1). Overwrites approx k.
__global__ __launch_bounds__(256) void rescore_kernel(const float* __restrict__ x,
                                                      const float* __restrict__ c,
                                                      const float* __restrict__ csq,
                                                      const int* __restrict__ gcnt,
                                                      const int* __restrict__ glist,
                                                      int list_cap,
                                                      float* __restrict__ out_assign) {
    int n = *gcnt;
    if (n > list_cap) n = list_cap;
    for (int idx = blockIdx.x * 256 + threadIdx.x; idx < n; idx += 256 * 256) {
        int i = glist[idx];
        float xv[DD];
        const float4* xp = (const float4*)(x + (size_t)i * DD);
#pragma unroll
        for (int q = 0; q < DD / 4; ++q) {
            float4 v = xp[q];
            xv[4 * q + 0] = v.x; xv[4 * q + 1] = v.y;
            xv[4 * q + 2] = v.z; xv[4 * q + 3] = v.w;
        }
        float r[8];
#pragma unroll
        for (int t = 0; t < 8; ++t) r[t] = __fmul_rn(xv[t], xv[t]);
#pragma unroll
        for (int b = 1; b < 8; ++b)
#pragma unroll
            for (int t = 0; t < 8; ++t)
                r[t] = __fadd_rn(r[t], __fmul_rn(xv[8 * b + t], xv[8 * b + t]));
        float x_sq = __fadd_rn(__fadd_rn(__fadd_rn(r[0], r[1]), __fadd_rn(r[2], r[3])),
                               __fadd_rn(__fadd_rn(r[4], r[5]), __fadd_rn(r[6], r[7])));
        float best = INFINITY;
        int best_k = 0;
        for (int k = 0; k < KC; ++k) {
            const float* crow = c + (size_t)k * DD;  // wave-uniform -> s_load
            float a0 = 0.f, a1 = 0.f, a2 = 0.f, a3 = 0.f;
#pragma unroll
            for (int d = 0; d < DD; d += 4) {
                a0 = __fmaf_rn(xv[d + 0], crow[d + 0], a0);
                a1 = __fmaf_rn(xv[d + 1], crow[d + 1], a1);
                a2 = __fmaf_rn(xv[d + 2], crow[d + 2], a2);
                a3 = __fmaf_rn(xv[d + 3], crow[d + 3], a3);
            }
            float acc = __fadd_rn(__fadd_rn(a0, a1), __fadd_rn(a2, a3));
            float t = __fadd_rn(x_sq, csq[k]);
            float dist = __fmaf_rn(-2.0f, acc, t);
            if (dist < best) { best = dist; best_k = k; }  // strict <: first wins
        }
        out_assign[i] = (float)best_k;
    }
}

// Fallback: repairs any SENTINEL left by list overflow (normally zero ->
// one coalesced read + ballot per wave, exits in a few us).
__global__ __launch_bounds__(256) void fallback_kernel(const float* __restrict__ x,
                                                       const float* __restrict__ c,
                                                       const float* __restrict__ csq,
                                                       float* __restrict__ out_assign) {
    int p = blockIdx.x * 256 + threadIdx.x;
    int lane = threadIdx.x & 63;
    float v = out_assign[p];
    unsigned long long mask = __ballot(v < 0.0f);
    int wbase = p & ~63;

    while (mask) {
        int b = __ffsll((long long)mask) - 1;
        mask &= mask - 1;
        int i = wbase + b;
        const float* xr = x + (size_t)i * DD;

        float r8[8];
#pragma unroll
        for (int e = 0; e < 8; ++e) r8[e] = __fmul_rn(xr[e], xr[e]);
#pragma unroll
        for (int blk = 1; blk < 8; ++blk)
#pragma unroll
            for (int e = 0; e < 8; ++e)
                r8[e] = __fadd_rn(r8[e], __fmul_rn(xr[8 * blk + e], xr[8 * blk + e]));
        float x_sq = __fadd_rn(__fadd_rn(__fadd_rn(r8[0], r8[1]), __fadd_rn(r8[2], r8[3])),
                               __fadd_rn(__fadd_rn(r8[4], r8[5]), __fadd_rn(r8[6], r8[7])));

        unsigned long long best = ~0ull;
#pragma unroll 1
        for (int j = 0; j < 8; ++j) {
            int k = j * 64 + lane;
            const float* crow = c + (size_t)k * DD;
            float a0 = 0.f, a1 = 0.f, a2 = 0.f, a3 = 0.f;
#pragma unroll
            for (int d = 0; d < DD; d += 4) {
                a0 = __fmaf_rn(xr[d + 0], crow[d + 0], a0);
                a1 = __fmaf_rn(xr[d + 1], crow[d + 1], a1);
                a2 = __fmaf_rn(xr[d + 2], crow[d + 2], a2);
                a3 = __fmaf_rn(xr[d + 3], crow[d + 3], a3);
            }
            float acc = __fadd_rn(__fadd_rn(a0, a1), __fadd_rn(a2, a3));
            float tt = __fadd_rn(x_sq, csq[k]);
            float dist = __fmaf_rn(-2.0f, acc, tt);
            unsigned long long key =
                ((unsigned long long)__float_as_uint(dist) << 32) | (unsigned)k;
            best = best < key ? best : key;
        }
#pragma unroll
        for (int dd = 1; dd < 64; dd <<= 1) {
            unsigned hi = (unsigned)__shfl_xor((int)(best >> 32), dd);
            unsigned lo = (unsigned)__shfl_xor((int)(best & 0xFFFFFFFFull), dd);
            unsigned long long o = ((unsigned long long)hi << 32) | lo;
            best = best < o ? best : o;
        }
        if (lane == 0) out_assign[i] = (float)(unsigned)(best & 0xFFFFFFFFull);
    }
}

extern "C" void kernel_launch(void* const* d_in, const int* in_sizes, int n_in,
                              void* d_out, int out_size, void* d_ws, size_t ws_size,
                              hipStream_t stream) {
    const float* x = (const float*)d_in[0];
    const float* c = (const float*)d_in[1];
    float* out = (float*)d_out;
    float* out_assign = out + KC * DD;

    char* ws = (char*)d_ws;
    int* gcnt = (int*)(ws + WS_GCNT);
    float* cs16 = (float*)(ws + WS_CS16);
    float* csq = (float*)(ws + WS_CSQ);
    _Float16* cf16 = (_Float16*)(ws + WS_CF16);
    int* glist = (int*)(ws + WS_LIST);
    int list_cap = 0;
    if (ws_size > WS_LIST + 4) {
        size_t cap = (ws_size - WS_LIST) / 4;
        list_cap = cap > NPTS ? NPTS : (int)cap;
    }

    hipMemsetAsync(gcnt, 0, 16, stream);
    prep_kernel<<<(KC * DD + 255) / 256, 256, 0, stream>>>(c, out, cf16, cs16, csq);
    approx_kernel<<<NPTS / 128, 256, 67584, stream>>>(x, cf16, cs16, out_assign,
                                                      gcnt, glist, list_cap);
    rescore_kernel<<<256, 256, 0, stream>>>(x, c, csq, gcnt, glist, list_cap,
                                            out_assign);
    fallback_kernel<<<NPTS / 256, 256, 0, stream>>>(x, c, csq, out_assign);
}